// Round 12
// baseline (221.908 us; speedup 1.0000x reference)
//
#include <hip/hip_runtime.h>
#include <math.h>

// Model: B=32, C=64, T=1024, H=10, OUT=2.
// R26 post-mortem: dual-chain NEUTRAL (115.5us) -> scan is ISSUE-bound at
// ~30 instrs/step. Parallel ~52us at ~22% VALU-busy on active CUs with
// 2 waves/SIMD -> LATENCY-bound (R20's diagnosis was right).
// KEY INSIGHT from R18/R20/R25 counters: the compiler's VGPR budget
// follows LDS-derived occupancy, not launch_bounds/waves_per_eu:
//   NT=512 +58.9KB -> 2 blk/CU -> 4 w/SIMD -> 128 VGPR (R18)
//   NT=1024+58.9KB -> 2 blk/CU -> 8 w/SIMD ->  64 VGPR (R20, spilled)
//   NT=512 +104KB  -> 1 blk/CU ->            128 VGPR (R25)
// R27: NT=1024 (16 waves, 1 timestep/thread; numerics proven absmax 0.0
// in R20-22) with LDS PADDED >80KB (kxl gets a dedicated 45KB array ->
// ~102KB total) -> 1 blk/CU -> 4 waves/SIMD -> 128 VGPR cap, need ~70,
// no spills. 2x latency hiding for the latency-bound parallel phase.
// Keeps: ftanh, rolled S3 (stride-11 conflict-free), dual-chain scan.
// Predict: WRITE ~104KB & VGPR ~72-90 (else 16-wave dead), LDS ~102KB,
// parallel 52->~30, dur 115.5 -> ~93-100us, absmax 0.

constexpr int B = 32, C = 64, T = 1024, H = 10;
constexpr int NT = 1024;  // 16 waves, ONE timestep per thread
constexpr int RS = 1028;  // scan-row stride (floats): 16B-aligned

struct Params {
  const float *beeg, *W_ef, *b_ef, *g_i, *be_i, *Wq, *g_q, *be_q, *Wk, *g_k,
      *be_k, *Wv, *g_v, *be_v, *Wc, *g_c, *be_c, *W_in, *W_rec, *W_cls, *b_cls;
  int* cnt;              // barrier counters (memset 0 each launch)
  double *P1, *P2, *P3;  // cross-block stat partials, layout [ch][32]
  float* out;
};

// DPP wave64 sum: result valid in lane 63 (VALU pipe, no DS traffic).
template <int CTRL>
__device__ inline float dadd(float v) {
  int x = __builtin_amdgcn_update_dpp(0, __float_as_int(v), CTRL, 0xf, 0xf,
                                      true);
  return v + __int_as_float(x);
}
__device__ inline float wred63(float v) {
  v = dadd<0x111>(v);  // row_shr:1
  v = dadd<0x112>(v);  // row_shr:2
  v = dadd<0x114>(v);  // row_shr:4
  v = dadd<0x118>(v);  // row_shr:8
  v = dadd<0x142>(v);  // row_bcast:15
  v = dadd<0x143>(v);  // row_bcast:31
  return v;            // lane 63 = full sum
}

// fast tanh: 1 - 2/(e^{2x}+1) via native exp2/rcp. ~1e-7 abs, branch-free.
// PROVEN absmax 0.0 in R23-R26.
__device__ inline float ftanh(float x) {
  float e = __builtin_amdgcn_exp2f(x * 2.8853900817779268f);  // e^{2x}
  float r = __builtin_amdgcn_rcpf(e + 1.0f);
  return fmaf(-2.0f, r, 1.0f);
}

// 32-block barrier, fence-free (all cross-block data via agent-scope atomics).
__device__ inline void gbar(int* cnt, int phase, int tid) {
  __syncthreads();
  if (tid == 0) {
    __hip_atomic_fetch_add(&cnt[phase], 1, __ATOMIC_RELEASE,
                           __HIP_MEMORY_SCOPE_AGENT);
    while (__hip_atomic_load(&cnt[phase], __ATOMIC_RELAXED,
                             __HIP_MEMORY_SCOPE_AGENT) < B)
      __builtin_amdgcn_s_sleep(2);
  }
  __syncthreads();
}

__global__ void __launch_bounds__(NT) fused19(Params p) {
  const int b = blockIdx.x, tid = threadIdx.x;
  const int lane = tid & 63, wid = tid >> 6;   // 16 waves

  __shared__ __align__(16) float slab[T * 11];   // scratch, then Iin [h][RS]
  __shared__ __align__(16) float gtab[T];        // 4KB
  __shared__ double dred2[60 * 17 + 4];          // combine partials (pad 17)
  __shared__ double dtot[60];
  __shared__ float stM[30], stI[30], Ms[100], Nl[100];
  __shared__ float kxl[NT * 11];                 // 45KB: S3 k-slots AND the
  // LDS pad that forces 1 blk/CU -> 4 waves/SIMD -> 128-VGPR budget.

  float* swred = slab;          // [16][60] stats scratch (dead before S5)
  float* mpw   = slab + 1024;   // [16][100] M partials (dead before S5)

  // g[t] = (9(1-0.9^{T-t}) - 4(1-0.8^{T-t})) / T  (f32 closed form)
  {
    const float L2A = -0.15200309344504995f;   // log2(0.9)
    const float L2D = -0.32192809488736235f;   // log2(0.8)
    float m0 = (float)(T - tid);
    gtab[tid] = (9.0f * (1.0f - exp2f(m0 * L2A)) -
                 4.0f * (1.0f - exp2f(m0 * L2D))) * (1.0f / (float)T);
  }

  // parallel stats combine: P layout [ch][32]; ch x 16 workers, 2 loads each.
  auto combine = [&](double* P, int Q2) {
    for (int id = tid; id < Q2 * 16; id += NT) {
      int ch = id >> 4, i = id & 15;
      double s = __hip_atomic_load(&P[ch * 32 + i], __ATOMIC_RELAXED,
                                   __HIP_MEMORY_SCOPE_AGENT) +
                 __hip_atomic_load(&P[ch * 32 + 16 + i], __ATOMIC_RELAXED,
                                   __HIP_MEMORY_SCOPE_AGENT);
      dred2[ch * 17 + i] = s;
    }
    __syncthreads();
    if (tid < Q2) {
      double s = 0.0;
#pragma unroll
      for (int i = 0; i < 16; ++i) s += dred2[tid * 17 + i];
      dtot[tid] = s;
    }
    __syncthreads();
  };

  // ---------------- S1: embed (weights via uniform/scalar loads)
  float p1[H];
#pragma unroll
  for (int h = 0; h < H; ++h) p1[h] = p.b_ef[h];
  {
    const float* bp = p.beeg + (size_t)b * C * T;
#pragma unroll 8
    for (int c = 0; c < C; ++c) {
      float v = bp[(size_t)c * T + tid];
#pragma unroll
      for (int h = 0; h < H; ++h)
        p1[h] = fmaf(v, p.W_ef[h * C + c], p1[h]);   // wave-uniform weight
    }
  }
#pragma unroll
  for (int h = 0; h < H; ++h) {
    float r1 = wred63(p1[h]);
    float r2 = wred63(p1[h] * p1[h]);
    if (lane == 63) { swred[wid * 60 + h] = r1; swred[wid * 60 + 10 + h] = r2; }
  }
  __syncthreads();
  if (tid < 20) {
    float s = 0.f;
#pragma unroll
    for (int w = 0; w < 16; ++w) s += swred[w * 60 + tid];
    __hip_atomic_store(&p.P1[tid * 32 + b], (double)s, __ATOMIC_RELAXED,
                       __HIP_MEMORY_SCOPE_AGENT);
  }
  gbar(p.cnt, 0, tid);
  combine(p.P1, 20);
  if (tid < 10) {
    double mean = dtot[tid] * (1.0 / 32768.0);
    double var  = dtot[10 + tid] * (1.0 / 32768.0) - mean * mean;
    stM[tid] = (float)mean;
    stI[tid] = (float)(1.0 / sqrt(var + 1e-5));
  }
  __syncthreads();

  // ---------------- S2: x = tanh(bn(pre1)); qkv stats (accumulators only)
  float xa[H];
#pragma unroll
  for (int j = 0; j < H; ++j)
    xa[j] = ftanh(p.g_i[j] * (p1[j] - stM[j]) * stI[j] + p.be_i[j]);
#pragma unroll
  for (int h = 0; h < H; ++h) {
    float qa = 0.f, ka = 0.f, va = 0.f;
#pragma unroll
    for (int j = 0; j < H; ++j) {
      qa = fmaf(xa[j], p.Wq[h * H + j], qa);
      ka = fmaf(xa[j], p.Wk[h * H + j], ka);
      va = fmaf(xa[j], p.Wv[h * H + j], va);
    }
    float r1 = wred63(qa), r2 = wred63(qa * qa);
    float r3 = wred63(ka), r4 = wred63(ka * ka);
    float r5 = wred63(va), r6 = wred63(va * va);
    if (lane == 63) {
      swred[wid * 60 + h]      = r1; swred[wid * 60 + 30 + h] = r2;
      swred[wid * 60 + 10 + h] = r3; swred[wid * 60 + 40 + h] = r4;
      swred[wid * 60 + 20 + h] = r5; swred[wid * 60 + 50 + h] = r6;
    }
  }
  __syncthreads();
  if (tid < 60) {
    float s = 0.f;
#pragma unroll
    for (int w = 0; w < 16; ++w) s += swred[w * 60 + tid];
    __hip_atomic_store(&p.P2[tid * 32 + b], (double)s, __ATOMIC_RELAXED,
                       __HIP_MEMORY_SCOPE_AGENT);
  }
  gbar(p.cnt, 1, tid);
  combine(p.P2, 60);
  if (tid < 30) {
    double mean = dtot[tid] * (1.0 / 32768.0);
    double var  = dtot[30 + tid] * (1.0 / 32768.0) - mean * mean;
    stM[tid] = (float)mean;
    stI[tid] = (float)(1.0 / sqrt(var + 1e-5));
  }
  __syncthreads();

  // ---------------- S3: M = KV^T, single pass, reduction ROLLED over i
  // (kx in dedicated LDS slots stride 11 = conflict-free; vx in regs so
  //  the unrolled j-index stays compile-time). R24-proven structure.
  {
    float vx[H];
#pragma unroll
    for (int h = 0; h < H; ++h) {
      float ka = 0.f, va = 0.f;
#pragma unroll
      for (int j = 0; j < H; ++j) {
        ka = fmaf(xa[j], p.Wk[h * H + j], ka);
        va = fmaf(xa[j], p.Wv[h * H + j], va);
      }
      kxl[tid * 11 + h] =
          fmaxf(p.g_k[h] * (ka - stM[10 + h]) * stI[10 + h] + p.be_k[h], 0.f);
      vx[h] = ftanh(p.g_v[h] * (va - stM[20 + h]) * stI[20 + h] + p.be_v[h]);
    }
#pragma unroll 1
    for (int i = 0; i < H; ++i) {
      float ki = kxl[tid * 11 + i];
#pragma unroll
      for (int j = 0; j < H; ++j) {
        float r = wred63(ki * vx[j]);
        if (lane == 63) mpw[wid * 100 + i * 10 + j] = r;
      }
    }
  }
  __syncthreads();
  if (tid < 100) {
    float s = 0.f;
#pragma unroll
    for (int w = 0; w < 16; ++w) s += mpw[w * 100 + tid];
    Ms[tid] = s;
  }
  __syncthreads();

  // ---------------- S4: N = (M Wc^T)/H; recompute q; prec = q . N
  if (tid < 100) {
    int i = tid / 10, h = tid % 10;
    float a = 0.f;
#pragma unroll
    for (int j = 0; j < H; ++j) a = fmaf(Ms[i * 10 + j], p.Wc[h * H + j], a);
    Nl[tid] = a * 0.1f;
  }
  __syncthreads();
  float pca[H];
  {
    float qv[H];
#pragma unroll
    for (int h = 0; h < H; ++h) {
      float qa = 0.f;
#pragma unroll
      for (int j = 0; j < H; ++j) qa = fmaf(xa[j], p.Wq[h * H + j], qa);
      qv[h] = fmaxf(p.g_q[h] * (qa - stM[h]) * stI[h] + p.be_q[h], 0.f);
    }
#pragma unroll
    for (int h = 0; h < H; ++h) {
      float a = 0.f;
#pragma unroll
      for (int i = 0; i < H; ++i) a = fmaf(qv[i], Nl[i * 10 + h], a);
      pca[h] = a;
    }
  }
#pragma unroll
  for (int h = 0; h < H; ++h) {
    float r1 = wred63(pca[h]);
    float r2 = wred63(pca[h] * pca[h]);
    if (lane == 63) { swred[wid * 60 + h] = r1; swred[wid * 60 + 10 + h] = r2; }
  }
  __syncthreads();
  if (tid < 20) {
    float s = 0.f;
#pragma unroll
    for (int w = 0; w < 16; ++w) s += swred[w * 60 + tid];
    __hip_atomic_store(&p.P3[tid * 32 + b], (double)s, __ATOMIC_RELAXED,
                       __HIP_MEMORY_SCOPE_AGENT);
  }
  gbar(p.cnt, 2, tid);
  combine(p.P3, 20);
  if (tid < 10) {
    double mean = dtot[tid] * (1.0 / 32768.0);
    double var  = dtot[10 + tid] * (1.0 / 32768.0) - mean * mean;
    stM[tid] = (float)mean;
    stI[tid] = (float)(1.0 / sqrt(var + 1e-5));
  }
  __syncthreads();   // all slab-scratch reads done before S5 overwrites

  // ---------------- S5: bn+relu, Iin into LDS rows [h][RS]
  {
    float ca[H];
#pragma unroll
    for (int j = 0; j < H; ++j)
      ca[j] = fmaxf(p.g_c[j] * (pca[j] - stM[j]) * stI[j] + p.be_c[j], 0.f);
#pragma unroll
    for (int h = 0; h < H; ++h) {
      float a = 0.f;
#pragma unroll
      for (int j = 0; j < H; ++j) a = fmaf(ca[j], p.W_in[h * H + j], a);
      slab[h * RS + tid] = a;
    }
  }
  __syncthreads();

  // ---------------- S6: LSNN scan, wave 0 only; dual fma chains + fused
  // decay (reassoc classes proven absmax 0.0 in R20-26).
  if (tid < 64) {
    // gtot closed form: .9^1024/.8^1024 underflow -> (5*1024 - 81 + 16)/1024
    const float gtot = 4.9365234375f;

    const int slot = lane < H ? lane : 0;   // inactive lanes broadcast row 0
    const float* row = slab + slot * RS;
    float wrf[H];                           // W_rec row (this lane's neuron)
#pragma unroll
    for (int j = 0; j < H; ++j)
      wrf[j] = (lane < H) ? p.W_rec[lane * H + j] : 0.f;

    float accp = 0.f, vm = 0.f, S = 0.f;    // accp = i_jump of prev step
    float zf = 0.f;   // prev-step spike, per-lane float (lane j holds z_j)

    auto step = [&](float iin, float gt) {
      float zj[H];
#pragma unroll
      for (int j = 0; j < H; ++j)
        zj[j] = __int_as_float(
            __builtin_amdgcn_readlane(__float_as_int(zf), j));
      float acc0 = fmaf(0.8f, accp, iin);   // fused decay
      float acc1 = 0.f;
#pragma unroll
      for (int j = 0; j < H; j += 2) {      // dual chains
        acc0 = fmaf(zj[j],     wrf[j],     acc0);
        acc1 = fmaf(zj[j + 1], wrf[j + 1], acc1);
      }
      float acc = acc0 + acc1;
      float v_dec = fmaf(0.1f, acc - vm, vm);  // vm + 0.1*(i_jump - vm)
      bool z = v_dec > 0.5f;
      vm = z ? 0.f : v_dec;
      zf = z ? 1.0f : 0.0f;
      S = fmaf(zf, gt, S);                     // exact: +gt or +0.0
      accp = acc;
    };

    float4 iA = *(const float4*)&row[0];
    float4 iB = *(const float4*)&row[4];
    float4 gA = *(const float4*)&gtab[0], gB = *(const float4*)&gtab[4];

    for (int t8 = 0; t8 < T - 8; t8 += 8) {
      float4 iN1 = *(const float4*)&row[t8 + 8];
      float4 iN2 = *(const float4*)&row[t8 + 12];
      float4 gN1 = *(const float4*)&gtab[t8 + 8];
      float4 gN2 = *(const float4*)&gtab[t8 + 12];
      step(iA.x, gA.x); step(iA.y, gA.y); step(iA.z, gA.z); step(iA.w, gA.w);
      step(iB.x, gB.x); step(iB.y, gB.y); step(iB.z, gB.z); step(iB.w, gB.w);
      iA = iN1; iB = iN2; gA = gN1; gB = gN2;
    }
    step(iA.x, gA.x); step(iA.y, gA.y); step(iA.z, gA.z); step(iA.w, gA.w);
    step(iB.x, gB.x); step(iB.y, gB.y); step(iB.z, gB.z); step(iB.w, gB.w);

    int li = lane < H ? lane : 0;
    float c0 = (lane < H) ? S * p.W_cls[li]     : 0.f;
    float c1 = (lane < H) ? S * p.W_cls[H + li] : 0.f;
    float r0 = wred63(c0), r1 = wred63(c1);
    if (lane == 63) {
      p.out[b * 2 + 0] = r0 + gtot * p.b_cls[0];
      p.out[b * 2 + 1] = r1 + gtot * p.b_cls[1];
    }
  }
}

extern "C" void kernel_launch(void* const* d_in, const int* in_sizes, int n_in,
                              void* d_out, int out_size, void* d_ws, size_t ws_size,
                              hipStream_t stream) {
  Params p;
  p.beeg  = (const float*)d_in[2];
  p.W_ef  = (const float*)d_in[4];
  p.b_ef  = (const float*)d_in[5];
  p.g_i   = (const float*)d_in[6];
  p.be_i  = (const float*)d_in[7];
  p.Wq    = (const float*)d_in[8];
  p.g_q   = (const float*)d_in[9];
  p.be_q  = (const float*)d_in[10];
  p.Wk    = (const float*)d_in[11];
  p.g_k   = (const float*)d_in[12];
  p.be_k  = (const float*)d_in[13];
  p.Wv    = (const float*)d_in[14];
  p.g_v   = (const float*)d_in[15];
  p.be_v  = (const float*)d_in[16];
  p.Wc    = (const float*)d_in[17];
  p.g_c   = (const float*)d_in[18];
  p.be_c  = (const float*)d_in[19];
  p.W_in  = (const float*)d_in[20];
  p.W_rec = (const float*)d_in[21];
  p.W_cls = (const float*)d_in[22];
  p.b_cls = (const float*)d_in[23];

  char* ws = (char*)d_ws;
  p.cnt = (int*)ws;                            // 3 counters, memset below
  p.P1  = (double*)(ws + 256);                 // [20][32] doubles
  p.P2  = (double*)(ws + 256 + 5120);          // [60][32] doubles
  p.P3  = (double*)(ws + 256 + 5120 + 15360);  // [20][32] doubles
  p.out = (float*)d_out;

  (void)hipMemsetAsync(d_ws, 0, 256, stream);  // zero barrier counters
  fused19<<<dim3(B), dim3(NT), 0, stream>>>(p);
}

// Round 13
// 207.252 us; speedup vs baseline: 1.0707x; 1.0707x over previous
//
#include <hip/hip_runtime.h>
#include <math.h>

// Model: B=32, C=64, T=1024, H=10, OUT=2.
// R27 post-mortem: LDS-pad did NOT unlock VGPR (still 64) but kernel fit
// (no spills); dur 123us WORSE. Parallel 52->60: with 1 t/thread each
// wave covers 64 timesteps -> per-wave reduction count FIXED while waves
// double -> total DPP work doubles. 2-t/thread amortizes reductions;
// 16-wave retired on evidence. Sharpened theory: parallel's fixed
// ~40-45us = per-wave serial DPP-reduction latency (300 wred63/wave,
// each ~12 dep instrs). R19/R27 consistent.
// R28: halve S3 reductions via merge-v2 = R25's merge (absmax 0.0 proven)
// minus R25's bugs: (a) kx TRANSPOSED [20][512] in slab -> consecutive
// lanes/banks, conflict-free, ZERO extra LDS (slab repacked: kxt[0,10240),
// mpw[10240,11040), swred aliases kxt w/ disjoint lifetimes); (b) only
// vxa/vxb in regs (+10 vs R26). S3: 200->100 wred63, one pass/sync less.
// Predict: VGPR ~85-100 w/ WRITE ~104KB (gate), LDS 58880, conflicts 0,
// parallel 52->~45 -> dur ~107-110 if theory right; neutral -> near floor.

constexpr int B = 32, C = 64, T = 1024, H = 10;
constexpr int NT = 512;   // threads per block (8 waves)
constexpr int RS = 1028;  // scan-row stride (floats): 16B-aligned

struct Params {
  const float *beeg, *W_ef, *b_ef, *g_i, *be_i, *Wq, *g_q, *be_q, *Wk, *g_k,
      *be_k, *Wv, *g_v, *be_v, *Wc, *g_c, *be_c, *W_in, *W_rec, *W_cls, *b_cls;
  int* cnt;              // barrier counters (memset 0 each launch)
  double *P1, *P2, *P3;  // cross-block stat partials, layout [ch][32]
  float* out;
};

// DPP wave64 sum: result valid in lane 63 (VALU pipe, no DS traffic).
template <int CTRL>
__device__ inline float dadd(float v) {
  int x = __builtin_amdgcn_update_dpp(0, __float_as_int(v), CTRL, 0xf, 0xf,
                                      true);
  return v + __int_as_float(x);
}
__device__ inline float wred63(float v) {
  v = dadd<0x111>(v);  // row_shr:1
  v = dadd<0x112>(v);  // row_shr:2
  v = dadd<0x114>(v);  // row_shr:4
  v = dadd<0x118>(v);  // row_shr:8
  v = dadd<0x142>(v);  // row_bcast:15
  v = dadd<0x143>(v);  // row_bcast:31
  return v;            // lane 63 = full sum
}

// fast tanh: 1 - 2/(e^{2x}+1) via native exp2/rcp. ~1e-7 abs, branch-free.
// PROVEN absmax 0.0 in R23-R27.
__device__ inline float ftanh(float x) {
  float e = __builtin_amdgcn_exp2f(x * 2.8853900817779268f);  // e^{2x}
  float r = __builtin_amdgcn_rcpf(e + 1.0f);
  return fmaf(-2.0f, r, 1.0f);
}

// 32-block barrier, fence-free (all cross-block data via agent-scope atomics).
__device__ inline void gbar(int* cnt, int phase, int tid) {
  __syncthreads();
  if (tid == 0) {
    __hip_atomic_fetch_add(&cnt[phase], 1, __ATOMIC_RELEASE,
                           __HIP_MEMORY_SCOPE_AGENT);
    while (__hip_atomic_load(&cnt[phase], __ATOMIC_RELAXED,
                             __HIP_MEMORY_SCOPE_AGENT) < B)
      __builtin_amdgcn_s_sleep(2);
  }
  __syncthreads();
}

__global__ void __launch_bounds__(NT) fused20(Params p) {
  const int b = blockIdx.x, tid = threadIdx.x;
  const int lane = tid & 63, wid = tid >> 6;   // 8 waves
  const int t0 = tid, t1 = tid + NT;

  __shared__ __align__(16) float slab[T * 11];   // scratch, then Iin [h][RS]
  __shared__ __align__(16) float gtab[T];        // 4KB
  __shared__ double dred2[60 * 17 + 4];          // combine partials (pad 17)
  __shared__ double dtot[60];
  __shared__ float stM[30], stI[30], Ms[100], Nl[100];

  // slab scratch layout (all dead before S5 overwrites the whole slab):
  //  swred [0,480)        : S1/S2/S4 stats partials (lifetime-disjoint
  //                         with kxt: swred's S2 read completes before S3
  //                         writes kxt; S4 writes swred after S3's reads)
  //  kxt   [0,10240)      : S3 transposed k-slots [20][512] (a:0-9,b:10-19)
  //  mpw   [10240,11040)  : S3 M partials [8][100]
  float* swred = slab;
  float* kxt   = slab;
  float* mpw   = slab + 10240;

  // g[t] = (9(1-0.9^{T-t}) - 4(1-0.8^{T-t})) / T  (f32 closed form)
  {
    const float L2A = -0.15200309344504995f;   // log2(0.9)
    const float L2D = -0.32192809488736235f;   // log2(0.8)
    float m0 = (float)(T - t0), m1 = (float)(T - t1);
    gtab[t0] = (9.0f * (1.0f - exp2f(m0 * L2A)) -
                4.0f * (1.0f - exp2f(m0 * L2D))) * (1.0f / (float)T);
    gtab[t1] = (9.0f * (1.0f - exp2f(m1 * L2A)) -
                4.0f * (1.0f - exp2f(m1 * L2D))) * (1.0f / (float)T);
  }

  // parallel stats combine: P layout [ch][32]; ch x 16 workers, 2 loads each.
  auto combine = [&](double* P, int Q2) {
    for (int id = tid; id < Q2 * 16; id += NT) {
      int ch = id >> 4, i = id & 15;
      double s = __hip_atomic_load(&P[ch * 32 + i], __ATOMIC_RELAXED,
                                   __HIP_MEMORY_SCOPE_AGENT) +
                 __hip_atomic_load(&P[ch * 32 + 16 + i], __ATOMIC_RELAXED,
                                   __HIP_MEMORY_SCOPE_AGENT);
      dred2[ch * 17 + i] = s;
    }
    __syncthreads();
    if (tid < Q2) {
      double s = 0.0;
#pragma unroll
      for (int i = 0; i < 16; ++i) s += dred2[tid * 17 + i];
      dtot[tid] = s;
    }
    __syncthreads();
  };

  // ---------------- S1: embed (weights via uniform/scalar loads)
  float p1a[H], p1b[H];
#pragma unroll
  for (int h = 0; h < H; ++h) { p1a[h] = p.b_ef[h]; p1b[h] = p.b_ef[h]; }
  {
    const float* bp = p.beeg + (size_t)b * C * T;
#pragma unroll 8
    for (int c = 0; c < C; ++c) {
      float va = bp[(size_t)c * T + t0];
      float vb = bp[(size_t)c * T + t1];
#pragma unroll
      for (int h = 0; h < H; ++h) {
        float w = p.W_ef[h * C + c];   // wave-uniform -> s_load
        p1a[h] = fmaf(va, w, p1a[h]);
        p1b[h] = fmaf(vb, w, p1b[h]);
      }
    }
  }
#pragma unroll
  for (int h = 0; h < H; ++h) {
    float r1 = wred63(p1a[h] + p1b[h]);
    float r2 = wred63(p1a[h] * p1a[h] + p1b[h] * p1b[h]);
    if (lane == 63) { swred[wid * 60 + h] = r1; swred[wid * 60 + 10 + h] = r2; }
  }
  __syncthreads();
  if (tid < 20) {
    float s = 0.f;
#pragma unroll
    for (int w = 0; w < 8; ++w) s += swred[w * 60 + tid];
    __hip_atomic_store(&p.P1[tid * 32 + b], (double)s, __ATOMIC_RELAXED,
                       __HIP_MEMORY_SCOPE_AGENT);
  }
  gbar(p.cnt, 0, tid);
  combine(p.P1, 20);
  if (tid < 10) {
    double mean = dtot[tid] * (1.0 / 32768.0);
    double var  = dtot[10 + tid] * (1.0 / 32768.0) - mean * mean;
    stM[tid] = (float)mean;
    stI[tid] = (float)(1.0 / sqrt(var + 1e-5));
  }
  __syncthreads();

  // ---------------- S2: x = tanh(bn(pre1)); qkv stats (accumulators only)
  float xa[H], xb[H];
#pragma unroll
  for (int j = 0; j < H; ++j) {
    xa[j] = ftanh(p.g_i[j] * (p1a[j] - stM[j]) * stI[j] + p.be_i[j]);
    xb[j] = ftanh(p.g_i[j] * (p1b[j] - stM[j]) * stI[j] + p.be_i[j]);
  }
  // p1a/p1b dead; only xa/xb (20 floats) persist from here on.
#pragma unroll
  for (int h = 0; h < H; ++h) {
    float qa = 0.f, qb = 0.f, ka = 0.f, kb = 0.f, va = 0.f, vb = 0.f;
#pragma unroll
    for (int j = 0; j < H; ++j) {
      float wq = p.Wq[h * H + j], wk = p.Wk[h * H + j], wv = p.Wv[h * H + j];
      qa = fmaf(xa[j], wq, qa); qb = fmaf(xb[j], wq, qb);
      ka = fmaf(xa[j], wk, ka); kb = fmaf(xb[j], wk, kb);
      va = fmaf(xa[j], wv, va); vb = fmaf(xb[j], wv, vb);
    }
    float r1 = wred63(qa + qb), r2 = wred63(qa * qa + qb * qb);
    float r3 = wred63(ka + kb), r4 = wred63(ka * ka + kb * kb);
    float r5 = wred63(va + vb), r6 = wred63(va * va + vb * vb);
    if (lane == 63) {
      swred[wid * 60 + h]      = r1; swred[wid * 60 + 30 + h] = r2;
      swred[wid * 60 + 10 + h] = r3; swred[wid * 60 + 40 + h] = r4;
      swred[wid * 60 + 20 + h] = r5; swred[wid * 60 + 50 + h] = r6;
    }
  }
  __syncthreads();
  if (tid < 60) {
    float s = 0.f;
#pragma unroll
    for (int w = 0; w < 8; ++w) s += swred[w * 60 + tid];
    __hip_atomic_store(&p.P2[tid * 32 + b], (double)s, __ATOMIC_RELAXED,
                       __HIP_MEMORY_SCOPE_AGENT);
  }
  gbar(p.cnt, 1, tid);
  combine(p.P2, 60);
  if (tid < 30) {
    double mean = dtot[tid] * (1.0 / 32768.0);
    double var  = dtot[30 + tid] * (1.0 / 32768.0) - mean * mean;
    stM[tid] = (float)mean;
    stI[tid] = (float)(1.0 / sqrt(var + 1e-5));
  }
  __syncthreads();   // swred reads done; kxt may now overwrite [0,480)

  // ---------------- S3: M = KV^T, MERGED single pass (R25 numerics,
  // R28 layout). kxt transposed [row][tid]: consecutive lanes ->
  // consecutive banks (conflict-free). vxa/vxb in regs (compile-time j).
  // wred63(fma(kia,vxa_j, kib*vxb_j)): 100 reductions instead of 200.
  {
    float vxa[H], vxb[H];
#pragma unroll
    for (int h = 0; h < H; ++h) {
      float ka = 0.f, va = 0.f, kb = 0.f, vb = 0.f;
#pragma unroll
      for (int j = 0; j < H; ++j) {
        float wk = p.Wk[h * H + j], wv = p.Wv[h * H + j];
        ka = fmaf(xa[j], wk, ka); kb = fmaf(xb[j], wk, kb);
        va = fmaf(xa[j], wv, va); vb = fmaf(xb[j], wv, vb);
      }
      kxt[h * NT + tid] =
          fmaxf(p.g_k[h] * (ka - stM[10 + h]) * stI[10 + h] + p.be_k[h], 0.f);
      kxt[(H + h) * NT + tid] =
          fmaxf(p.g_k[h] * (kb - stM[10 + h]) * stI[10 + h] + p.be_k[h], 0.f);
      vxa[h] = ftanh(p.g_v[h] * (va - stM[20 + h]) * stI[20 + h] + p.be_v[h]);
      vxb[h] = ftanh(p.g_v[h] * (vb - stM[20 + h]) * stI[20 + h] + p.be_v[h]);
    }
    __syncthreads();   // kxt writes visible (also orders vs swred aliasing)
#pragma unroll 1
    for (int i = 0; i < H; ++i) {
      float kia = kxt[i * NT + tid];
      float kib = kxt[(H + i) * NT + tid];
#pragma unroll
      for (int j = 0; j < H; ++j) {
        float r = wred63(fmaf(kia, vxa[j], kib * vxb[j]));
        if (lane == 63) mpw[wid * 100 + i * 10 + j] = r;
      }
    }
  }
  __syncthreads();
  if (tid < 100) {
    float s = 0.f;
#pragma unroll
    for (int w = 0; w < 8; ++w) s += mpw[w * 100 + tid];
    Ms[tid] = s;
  }
  __syncthreads();

  // ---------------- S4: N = (M Wc^T)/H; recompute q; prec = q . N
  if (tid < 100) {
    int i = tid / 10, h = tid % 10;
    float a = 0.f;
#pragma unroll
    for (int j = 0; j < H; ++j) a = fmaf(Ms[i * 10 + j], p.Wc[h * H + j], a);
    Nl[tid] = a * 0.1f;
  }
  __syncthreads();
  float pca[H], pcb[H];
  {  // pass a
    float qv[H];
#pragma unroll
    for (int h = 0; h < H; ++h) {
      float qa = 0.f;
#pragma unroll
      for (int j = 0; j < H; ++j) qa = fmaf(xa[j], p.Wq[h * H + j], qa);
      qv[h] = fmaxf(p.g_q[h] * (qa - stM[h]) * stI[h] + p.be_q[h], 0.f);
    }
#pragma unroll
    for (int h = 0; h < H; ++h) {
      float a = 0.f;
#pragma unroll
      for (int i = 0; i < H; ++i) a = fmaf(qv[i], Nl[i * 10 + h], a);
      pca[h] = a;
    }
  }
  {  // pass b
    float qv[H];
#pragma unroll
    for (int h = 0; h < H; ++h) {
      float qb = 0.f;
#pragma unroll
      for (int j = 0; j < H; ++j) qb = fmaf(xb[j], p.Wq[h * H + j], qb);
      qv[h] = fmaxf(p.g_q[h] * (qb - stM[h]) * stI[h] + p.be_q[h], 0.f);
    }
#pragma unroll
    for (int h = 0; h < H; ++h) {
      float a = 0.f;
#pragma unroll
      for (int i = 0; i < H; ++i) a = fmaf(qv[i], Nl[i * 10 + h], a);
      pcb[h] = a;
    }
  }
  // xa/xb dead now; pca/pcb (20 floats) live. S4 may write swred (aliases
  // kxt, whose last read was before the mpw-sum syncthreads above).
#pragma unroll
  for (int h = 0; h < H; ++h) {
    float r1 = wred63(pca[h] + pcb[h]);
    float r2 = wred63(pca[h] * pca[h] + pcb[h] * pcb[h]);
    if (lane == 63) { swred[wid * 60 + h] = r1; swred[wid * 60 + 10 + h] = r2; }
  }
  __syncthreads();
  if (tid < 20) {
    float s = 0.f;
#pragma unroll
    for (int w = 0; w < 8; ++w) s += swred[w * 60 + tid];
    __hip_atomic_store(&p.P3[tid * 32 + b], (double)s, __ATOMIC_RELAXED,
                       __HIP_MEMORY_SCOPE_AGENT);
  }
  gbar(p.cnt, 2, tid);
  combine(p.P3, 20);
  if (tid < 10) {
    double mean = dtot[tid] * (1.0 / 32768.0);
    double var  = dtot[10 + tid] * (1.0 / 32768.0) - mean * mean;
    stM[tid] = (float)mean;
    stI[tid] = (float)(1.0 / sqrt(var + 1e-5));
  }
  __syncthreads();   // all slab-scratch reads done before S5 overwrites

  // ---------------- S5: bn+relu, Iin into LDS rows [h][RS]
  {
    float ca[H];
#pragma unroll
    for (int j = 0; j < H; ++j)
      ca[j] = fmaxf(p.g_c[j] * (pca[j] - stM[j]) * stI[j] + p.be_c[j], 0.f);
#pragma unroll
    for (int h = 0; h < H; ++h) {
      float a = 0.f;
#pragma unroll
      for (int j = 0; j < H; ++j) a = fmaf(ca[j], p.W_in[h * H + j], a);
      slab[h * RS + t0] = a;
    }
#pragma unroll
    for (int j = 0; j < H; ++j)
      ca[j] = fmaxf(p.g_c[j] * (pcb[j] - stM[j]) * stI[j] + p.be_c[j], 0.f);
#pragma unroll
    for (int h = 0; h < H; ++h) {
      float a = 0.f;
#pragma unroll
      for (int j = 0; j < H; ++j) a = fmaf(ca[j], p.W_in[h * H + j], a);
      slab[h * RS + t1] = a;
    }
  }
  __syncthreads();

  // ---------------- S6: LSNN scan, wave 0 only; dual fma chains + fused
  // decay (reassoc classes proven absmax 0.0 in R20-27).
  if (tid < 64) {
    // gtot closed form: .9^1024/.8^1024 underflow -> (5*1024 - 81 + 16)/1024
    const float gtot = 4.9365234375f;

    const int slot = lane < H ? lane : 0;   // inactive lanes broadcast row 0
    const float* row = slab + slot * RS;
    float wrf[H];                           // W_rec row (this lane's neuron)
#pragma unroll
    for (int j = 0; j < H; ++j)
      wrf[j] = (lane < H) ? p.W_rec[lane * H + j] : 0.f;

    float accp = 0.f, vm = 0.f, S = 0.f;    // accp = i_jump of prev step
    float zf = 0.f;   // prev-step spike, per-lane float (lane j holds z_j)

    auto step = [&](float iin, float gt) {
      float zj[H];
#pragma unroll
      for (int j = 0; j < H; ++j)
        zj[j] = __int_as_float(
            __builtin_amdgcn_readlane(__float_as_int(zf), j));
      float acc0 = fmaf(0.8f, accp, iin);   // fused decay
      float acc1 = 0.f;
#pragma unroll
      for (int j = 0; j < H; j += 2) {      // dual chains
        acc0 = fmaf(zj[j],     wrf[j],     acc0);
        acc1 = fmaf(zj[j + 1], wrf[j + 1], acc1);
      }
      float acc = acc0 + acc1;
      float v_dec = fmaf(0.1f, acc - vm, vm);  // vm + 0.1*(i_jump - vm)
      bool z = v_dec > 0.5f;
      vm = z ? 0.f : v_dec;
      zf = z ? 1.0f : 0.0f;
      S = fmaf(zf, gt, S);                     // exact: +gt or +0.0
      accp = acc;
    };

    float4 iA = *(const float4*)&row[0];
    float4 iB = *(const float4*)&row[4];
    float4 gA = *(const float4*)&gtab[0], gB = *(const float4*)&gtab[4];

    for (int t8 = 0; t8 < T - 8; t8 += 8) {
      float4 iN1 = *(const float4*)&row[t8 + 8];
      float4 iN2 = *(const float4*)&row[t8 + 12];
      float4 gN1 = *(const float4*)&gtab[t8 + 8];
      float4 gN2 = *(const float4*)&gtab[t8 + 12];
      step(iA.x, gA.x); step(iA.y, gA.y); step(iA.z, gA.z); step(iA.w, gA.w);
      step(iB.x, gB.x); step(iB.y, gB.y); step(iB.z, gB.z); step(iB.w, gB.w);
      iA = iN1; iB = iN2; gA = gN1; gB = gN2;
    }
    step(iA.x, gA.x); step(iA.y, gA.y); step(iA.z, gA.z); step(iA.w, gA.w);
    step(iB.x, gB.x); step(iB.y, gB.y); step(iB.z, gB.z); step(iB.w, gB.w);

    int li = lane < H ? lane : 0;
    float c0 = (lane < H) ? S * p.W_cls[li]     : 0.f;
    float c1 = (lane < H) ? S * p.W_cls[H + li] : 0.f;
    float r0 = wred63(c0), r1 = wred63(c1);
    if (lane == 63) {
      p.out[b * 2 + 0] = r0 + gtot * p.b_cls[0];
      p.out[b * 2 + 1] = r1 + gtot * p.b_cls[1];
    }
  }
}

extern "C" void kernel_launch(void* const* d_in, const int* in_sizes, int n_in,
                              void* d_out, int out_size, void* d_ws, size_t ws_size,
                              hipStream_t stream) {
  Params p;
  p.beeg  = (const float*)d_in[2];
  p.W_ef  = (const float*)d_in[4];
  p.b_ef  = (const float*)d_in[5];
  p.g_i   = (const float*)d_in[6];
  p.be_i  = (const float*)d_in[7];
  p.Wq    = (const float*)d_in[8];
  p.g_q   = (const float*)d_in[9];
  p.be_q  = (const float*)d_in[10];
  p.Wk    = (const float*)d_in[11];
  p.g_k   = (const float*)d_in[12];
  p.be_k  = (const float*)d_in[13];
  p.Wv    = (const float*)d_in[14];
  p.g_v   = (const float*)d_in[15];
  p.be_v  = (const float*)d_in[16];
  p.Wc    = (const float*)d_in[17];
  p.g_c   = (const float*)d_in[18];
  p.be_c  = (const float*)d_in[19];
  p.W_in  = (const float*)d_in[20];
  p.W_rec = (const float*)d_in[21];
  p.W_cls = (const float*)d_in[22];
  p.b_cls = (const float*)d_in[23];

  char* ws = (char*)d_ws;
  p.cnt = (int*)ws;                            // 3 counters, memset below
  p.P1  = (double*)(ws + 256);                 // [20][32] doubles
  p.P2  = (double*)(ws + 256 + 5120);          // [60][32] doubles
  p.P3  = (double*)(ws + 256 + 5120 + 15360);  // [20][32] doubles
  p.out = (float*)d_out;

  (void)hipMemsetAsync(d_ws, 0, 256, stream);  // zero barrier counters
  fused20<<<dim3(B), dim3(NT), 0, stream>>>(p);
}

// Round 14
// 198.831 us; speedup vs baseline: 1.1161x; 1.0424x over previous
//
#include <hip/hip_runtime.h>
#include <math.h>

// Model: B=32, C=64, T=1024, H=10, OUT=2.
// R28 post-mortem: WIN 115.5->103.7us (merged S3: 200->100 wred63, ~12us).
// Reduction-latency theory holds quantitatively. Split: parallel ~41,
// scan ~63 (at its ~28-instr floor). Remaining stats reductions (S1 20,
// S2 60, S4 20) not mergeable (distinct stats).
// R29 = R28 + ONE change: pack all dual-timestep (a,b) FMA pairs into
// ext_vector float2 -> v_pk_fma_f32 (CDNA4 2-wide packed f32). Halves
// S1/S2/S3-mat/S4/S5 FMA issue (~1450 instrs/thread saved); S4's two
// passes merge into one. Per-component ops/order IDENTICAL -> bit-exact.
// Reductions/BN/tanh stay scalar on .x/.y extracts.
// Predict: VGPR ~90-110 (GATE: WRITE stays ~104KB else revert), parallel
// 41->~35, dur 103.7 -> ~96-100us, absmax 0. Neutral -> parallel is
// latency/sync-bound; instrument next.

constexpr int B = 32, C = 64, T = 1024, H = 10;
constexpr int NT = 512;   // threads per block (8 waves)
constexpr int RS = 1028;  // scan-row stride (floats): 16B-aligned

using v2f = float __attribute__((ext_vector_type(2)));
__device__ inline v2f v2(float s) { v2f r; r.x = s; r.y = s; return r; }
__device__ inline v2f vfma(v2f a, v2f b, v2f c) {
  return __builtin_elementwise_fma(a, b, c);   // v_pk_fma_f32
}

struct Params {
  const float *beeg, *W_ef, *b_ef, *g_i, *be_i, *Wq, *g_q, *be_q, *Wk, *g_k,
      *be_k, *Wv, *g_v, *be_v, *Wc, *g_c, *be_c, *W_in, *W_rec, *W_cls, *b_cls;
  int* cnt;              // barrier counters (memset 0 each launch)
  double *P1, *P2, *P3;  // cross-block stat partials, layout [ch][32]
  float* out;
};

// DPP wave64 sum: result valid in lane 63 (VALU pipe, no DS traffic).
template <int CTRL>
__device__ inline float dadd(float v) {
  int x = __builtin_amdgcn_update_dpp(0, __float_as_int(v), CTRL, 0xf, 0xf,
                                      true);
  return v + __int_as_float(x);
}
__device__ inline float wred63(float v) {
  v = dadd<0x111>(v);  // row_shr:1
  v = dadd<0x112>(v);  // row_shr:2
  v = dadd<0x114>(v);  // row_shr:4
  v = dadd<0x118>(v);  // row_shr:8
  v = dadd<0x142>(v);  // row_bcast:15
  v = dadd<0x143>(v);  // row_bcast:31
  return v;            // lane 63 = full sum
}

// fast tanh: 1 - 2/(e^{2x}+1) via native exp2/rcp. ~1e-7 abs, branch-free.
// PROVEN absmax 0.0 in R23-R28.
__device__ inline float ftanh(float x) {
  float e = __builtin_amdgcn_exp2f(x * 2.8853900817779268f);  // e^{2x}
  float r = __builtin_amdgcn_rcpf(e + 1.0f);
  return fmaf(-2.0f, r, 1.0f);
}

// 32-block barrier, fence-free (all cross-block data via agent-scope atomics).
__device__ inline void gbar(int* cnt, int phase, int tid) {
  __syncthreads();
  if (tid == 0) {
    __hip_atomic_fetch_add(&cnt[phase], 1, __ATOMIC_RELEASE,
                           __HIP_MEMORY_SCOPE_AGENT);
    while (__hip_atomic_load(&cnt[phase], __ATOMIC_RELAXED,
                             __HIP_MEMORY_SCOPE_AGENT) < B)
      __builtin_amdgcn_s_sleep(2);
  }
  __syncthreads();
}

__global__ void __launch_bounds__(NT) fused21(Params p) {
  const int b = blockIdx.x, tid = threadIdx.x;
  const int lane = tid & 63, wid = tid >> 6;   // 8 waves
  const int t0 = tid, t1 = tid + NT;

  __shared__ __align__(16) float slab[T * 11];   // scratch, then Iin [h][RS]
  __shared__ __align__(16) float gtab[T];        // 4KB
  __shared__ double dred2[60 * 17 + 4];          // combine partials (pad 17)
  __shared__ double dtot[60];
  __shared__ float stM[30], stI[30], Ms[100], Nl[100];

  // slab scratch layout (all dead before S5 overwrites the whole slab):
  //  swred [0,480) | kxt [0,10240) (lifetime-disjoint) | mpw [10240,11040)
  float* swred = slab;
  float* kxt   = slab;
  float* mpw   = slab + 10240;

  // g[t] = (9(1-0.9^{T-t}) - 4(1-0.8^{T-t})) / T  (f32 closed form)
  {
    const float L2A = -0.15200309344504995f;   // log2(0.9)
    const float L2D = -0.32192809488736235f;   // log2(0.8)
    float m0 = (float)(T - t0), m1 = (float)(T - t1);
    gtab[t0] = (9.0f * (1.0f - exp2f(m0 * L2A)) -
                4.0f * (1.0f - exp2f(m0 * L2D))) * (1.0f / (float)T);
    gtab[t1] = (9.0f * (1.0f - exp2f(m1 * L2A)) -
                4.0f * (1.0f - exp2f(m1 * L2D))) * (1.0f / (float)T);
  }

  // parallel stats combine: P layout [ch][32]; ch x 16 workers, 2 loads each.
  auto combine = [&](double* P, int Q2) {
    for (int id = tid; id < Q2 * 16; id += NT) {
      int ch = id >> 4, i = id & 15;
      double s = __hip_atomic_load(&P[ch * 32 + i], __ATOMIC_RELAXED,
                                   __HIP_MEMORY_SCOPE_AGENT) +
                 __hip_atomic_load(&P[ch * 32 + 16 + i], __ATOMIC_RELAXED,
                                   __HIP_MEMORY_SCOPE_AGENT);
      dred2[ch * 17 + i] = s;
    }
    __syncthreads();
    if (tid < Q2) {
      double s = 0.0;
#pragma unroll
      for (int i = 0; i < 16; ++i) s += dred2[tid * 17 + i];
      dtot[tid] = s;
    }
    __syncthreads();
  };

  // ---------------- S1: embed (weights via uniform/scalar loads; pk-fma)
  v2f p1[H];
#pragma unroll
  for (int h = 0; h < H; ++h) p1[h] = v2(p.b_ef[h]);
  {
    const float* bp = p.beeg + (size_t)b * C * T;
#pragma unroll 8
    for (int c = 0; c < C; ++c) {
      v2f vab;
      vab.x = bp[(size_t)c * T + t0];
      vab.y = bp[(size_t)c * T + t1];
#pragma unroll
      for (int h = 0; h < H; ++h)
        p1[h] = vfma(vab, v2(p.W_ef[h * C + c]), p1[h]);
    }
  }
#pragma unroll
  for (int h = 0; h < H; ++h) {
    float r1 = wred63(p1[h].x + p1[h].y);
    float r2 = wred63(p1[h].x * p1[h].x + p1[h].y * p1[h].y);
    if (lane == 63) { swred[wid * 60 + h] = r1; swred[wid * 60 + 10 + h] = r2; }
  }
  __syncthreads();
  if (tid < 20) {
    float s = 0.f;
#pragma unroll
    for (int w = 0; w < 8; ++w) s += swred[w * 60 + tid];
    __hip_atomic_store(&p.P1[tid * 32 + b], (double)s, __ATOMIC_RELAXED,
                       __HIP_MEMORY_SCOPE_AGENT);
  }
  gbar(p.cnt, 0, tid);
  combine(p.P1, 20);
  if (tid < 10) {
    double mean = dtot[tid] * (1.0 / 32768.0);
    double var  = dtot[10 + tid] * (1.0 / 32768.0) - mean * mean;
    stM[tid] = (float)mean;
    stI[tid] = (float)(1.0 / sqrt(var + 1e-5));
  }
  __syncthreads();

  // ---------------- S2: x = tanh(bn(pre1)); qkv stats (pk-fma accums)
  v2f xv[H];
#pragma unroll
  for (int j = 0; j < H; ++j) {
    xv[j].x = ftanh(p.g_i[j] * (p1[j].x - stM[j]) * stI[j] + p.be_i[j]);
    xv[j].y = ftanh(p.g_i[j] * (p1[j].y - stM[j]) * stI[j] + p.be_i[j]);
  }
  // p1 dead; only xv (10 v2f) persists from here on.
#pragma unroll
  for (int h = 0; h < H; ++h) {
    v2f q = v2(0.f), k = v2(0.f), v = v2(0.f);
#pragma unroll
    for (int j = 0; j < H; ++j) {
      q = vfma(xv[j], v2(p.Wq[h * H + j]), q);
      k = vfma(xv[j], v2(p.Wk[h * H + j]), k);
      v = vfma(xv[j], v2(p.Wv[h * H + j]), v);
    }
    float r1 = wred63(q.x + q.y), r2 = wred63(q.x * q.x + q.y * q.y);
    float r3 = wred63(k.x + k.y), r4 = wred63(k.x * k.x + k.y * k.y);
    float r5 = wred63(v.x + v.y), r6 = wred63(v.x * v.x + v.y * v.y);
    if (lane == 63) {
      swred[wid * 60 + h]      = r1; swred[wid * 60 + 30 + h] = r2;
      swred[wid * 60 + 10 + h] = r3; swred[wid * 60 + 40 + h] = r4;
      swred[wid * 60 + 20 + h] = r5; swred[wid * 60 + 50 + h] = r6;
    }
  }
  __syncthreads();
  if (tid < 60) {
    float s = 0.f;
#pragma unroll
    for (int w = 0; w < 8; ++w) s += swred[w * 60 + tid];
    __hip_atomic_store(&p.P2[tid * 32 + b], (double)s, __ATOMIC_RELAXED,
                       __HIP_MEMORY_SCOPE_AGENT);
  }
  gbar(p.cnt, 1, tid);
  combine(p.P2, 60);
  if (tid < 30) {
    double mean = dtot[tid] * (1.0 / 32768.0);
    double var  = dtot[30 + tid] * (1.0 / 32768.0) - mean * mean;
    stM[tid] = (float)mean;
    stI[tid] = (float)(1.0 / sqrt(var + 1e-5));
  }
  __syncthreads();   // swred reads done; kxt may now overwrite [0,480)

  // ---------------- S3: M = KV^T, merged single pass (R28 structure,
  // pk-fma mats). kxt transposed [20][512]: conflict-free.
  {
    v2f vx[H];   // (vxa, vxb)
#pragma unroll
    for (int h = 0; h < H; ++h) {
      v2f k = v2(0.f), v = v2(0.f);
#pragma unroll
      for (int j = 0; j < H; ++j) {
        k = vfma(xv[j], v2(p.Wk[h * H + j]), k);
        v = vfma(xv[j], v2(p.Wv[h * H + j]), v);
      }
      kxt[h * NT + tid] =
          fmaxf(p.g_k[h] * (k.x - stM[10 + h]) * stI[10 + h] + p.be_k[h], 0.f);
      kxt[(H + h) * NT + tid] =
          fmaxf(p.g_k[h] * (k.y - stM[10 + h]) * stI[10 + h] + p.be_k[h], 0.f);
      vx[h].x = ftanh(p.g_v[h] * (v.x - stM[20 + h]) * stI[20 + h] + p.be_v[h]);
      vx[h].y = ftanh(p.g_v[h] * (v.y - stM[20 + h]) * stI[20 + h] + p.be_v[h]);
    }
    __syncthreads();   // kxt writes visible (also orders vs swred aliasing)
#pragma unroll 1
    for (int i = 0; i < H; ++i) {
      float kia = kxt[i * NT + tid];
      float kib = kxt[(H + i) * NT + tid];
#pragma unroll
      for (int j = 0; j < H; ++j) {
        float r = wred63(fmaf(kia, vx[j].x, kib * vx[j].y));
        if (lane == 63) mpw[wid * 100 + i * 10 + j] = r;
      }
    }
  }
  __syncthreads();
  if (tid < 100) {
    float s = 0.f;
#pragma unroll
    for (int w = 0; w < 8; ++w) s += mpw[w * 100 + tid];
    Ms[tid] = s;
  }
  __syncthreads();

  // ---------------- S4: N = (M Wc^T)/H; recompute q; prec = q.N (pk, one
  // pass -- per-component ops/order identical to R28's two passes)
  if (tid < 100) {
    int i = tid / 10, h = tid % 10;
    float a = 0.f;
#pragma unroll
    for (int j = 0; j < H; ++j) a = fmaf(Ms[i * 10 + j], p.Wc[h * H + j], a);
    Nl[tid] = a * 0.1f;
  }
  __syncthreads();
  v2f pc[H];
  {
    v2f qv[H];
#pragma unroll
    for (int h = 0; h < H; ++h) {
      v2f qa = v2(0.f);
#pragma unroll
      for (int j = 0; j < H; ++j) qa = vfma(xv[j], v2(p.Wq[h * H + j]), qa);
      qv[h].x = fmaxf(p.g_q[h] * (qa.x - stM[h]) * stI[h] + p.be_q[h], 0.f);
      qv[h].y = fmaxf(p.g_q[h] * (qa.y - stM[h]) * stI[h] + p.be_q[h], 0.f);
    }
#pragma unroll
    for (int h = 0; h < H; ++h) {
      v2f a = v2(0.f);
#pragma unroll
      for (int i = 0; i < H; ++i) a = vfma(qv[i], v2(Nl[i * 10 + h]), a);
      pc[h] = a;
    }
  }
  // xv dead now; pc (10 v2f) live.
#pragma unroll
  for (int h = 0; h < H; ++h) {
    float r1 = wred63(pc[h].x + pc[h].y);
    float r2 = wred63(pc[h].x * pc[h].x + pc[h].y * pc[h].y);
    if (lane == 63) { swred[wid * 60 + h] = r1; swred[wid * 60 + 10 + h] = r2; }
  }
  __syncthreads();
  if (tid < 20) {
    float s = 0.f;
#pragma unroll
    for (int w = 0; w < 8; ++w) s += swred[w * 60 + tid];
    __hip_atomic_store(&p.P3[tid * 32 + b], (double)s, __ATOMIC_RELAXED,
                       __HIP_MEMORY_SCOPE_AGENT);
  }
  gbar(p.cnt, 2, tid);
  combine(p.P3, 20);
  if (tid < 10) {
    double mean = dtot[tid] * (1.0 / 32768.0);
    double var  = dtot[10 + tid] * (1.0 / 32768.0) - mean * mean;
    stM[tid] = (float)mean;
    stI[tid] = (float)(1.0 / sqrt(var + 1e-5));
  }
  __syncthreads();   // all slab-scratch reads done before S5 overwrites

  // ---------------- S5: bn+relu, Iin into LDS rows [h][RS] (pk-fma)
  {
    v2f ca[H];
#pragma unroll
    for (int j = 0; j < H; ++j) {
      ca[j].x = fmaxf(p.g_c[j] * (pc[j].x - stM[j]) * stI[j] + p.be_c[j], 0.f);
      ca[j].y = fmaxf(p.g_c[j] * (pc[j].y - stM[j]) * stI[j] + p.be_c[j], 0.f);
    }
#pragma unroll
    for (int h = 0; h < H; ++h) {
      v2f a = v2(0.f);
#pragma unroll
      for (int j = 0; j < H; ++j) a = vfma(ca[j], v2(p.W_in[h * H + j]), a);
      slab[h * RS + t0] = a.x;
      slab[h * RS + t1] = a.y;
    }
  }
  __syncthreads();

  // ---------------- S6: LSNN scan, wave 0 only; dual fma chains + fused
  // decay (reassoc classes proven absmax 0.0 in R20-28).
  if (tid < 64) {
    // gtot closed form: .9^1024/.8^1024 underflow -> (5*1024 - 81 + 16)/1024
    const float gtot = 4.9365234375f;

    const int slot = lane < H ? lane : 0;   // inactive lanes broadcast row 0
    const float* row = slab + slot * RS;
    float wrf[H];                           // W_rec row (this lane's neuron)
#pragma unroll
    for (int j = 0; j < H; ++j)
      wrf[j] = (lane < H) ? p.W_rec[lane * H + j] : 0.f;

    float accp = 0.f, vm = 0.f, S = 0.f;    // accp = i_jump of prev step
    float zf = 0.f;   // prev-step spike, per-lane float (lane j holds z_j)

    auto step = [&](float iin, float gt) {
      float zj[H];
#pragma unroll
      for (int j = 0; j < H; ++j)
        zj[j] = __int_as_float(
            __builtin_amdgcn_readlane(__float_as_int(zf), j));
      float acc0 = fmaf(0.8f, accp, iin);   // fused decay
      float acc1 = 0.f;
#pragma unroll
      for (int j = 0; j < H; j += 2) {      // dual chains
        acc0 = fmaf(zj[j],     wrf[j],     acc0);
        acc1 = fmaf(zj[j + 1], wrf[j + 1], acc1);
      }
      float acc = acc0 + acc1;
      float v_dec = fmaf(0.1f, acc - vm, vm);  // vm + 0.1*(i_jump - vm)
      bool z = v_dec > 0.5f;
      vm = z ? 0.f : v_dec;
      zf = z ? 1.0f : 0.0f;
      S = fmaf(zf, gt, S);                     // exact: +gt or +0.0
      accp = acc;
    };

    float4 iA = *(const float4*)&row[0];
    float4 iB = *(const float4*)&row[4];
    float4 gA = *(const float4*)&gtab[0], gB = *(const float4*)&gtab[4];

    for (int t8 = 0; t8 < T - 8; t8 += 8) {
      float4 iN1 = *(const float4*)&row[t8 + 8];
      float4 iN2 = *(const float4*)&row[t8 + 12];
      float4 gN1 = *(const float4*)&gtab[t8 + 8];
      float4 gN2 = *(const float4*)&gtab[t8 + 12];
      step(iA.x, gA.x); step(iA.y, gA.y); step(iA.z, gA.z); step(iA.w, gA.w);
      step(iB.x, gB.x); step(iB.y, gB.y); step(iB.z, gB.z); step(iB.w, gB.w);
      iA = iN1; iB = iN2; gA = gN1; gB = gN2;
    }
    step(iA.x, gA.x); step(iA.y, gA.y); step(iA.z, gA.z); step(iA.w, gA.w);
    step(iB.x, gB.x); step(iB.y, gB.y); step(iB.z, gB.z); step(iB.w, gB.w);

    int li = lane < H ? lane : 0;
    float c0 = (lane < H) ? S * p.W_cls[li]     : 0.f;
    float c1 = (lane < H) ? S * p.W_cls[H + li] : 0.f;
    float r0 = wred63(c0), r1 = wred63(c1);
    if (lane == 63) {
      p.out[b * 2 + 0] = r0 + gtot * p.b_cls[0];
      p.out[b * 2 + 1] = r1 + gtot * p.b_cls[1];
    }
  }
}

extern "C" void kernel_launch(void* const* d_in, const int* in_sizes, int n_in,
                              void* d_out, int out_size, void* d_ws, size_t ws_size,
                              hipStream_t stream) {
  Params p;
  p.beeg  = (const float*)d_in[2];
  p.W_ef  = (const float*)d_in[4];
  p.b_ef  = (const float*)d_in[5];
  p.g_i   = (const float*)d_in[6];
  p.be_i  = (const float*)d_in[7];
  p.Wq    = (const float*)d_in[8];
  p.g_q   = (const float*)d_in[9];
  p.be_q  = (const float*)d_in[10];
  p.Wk    = (const float*)d_in[11];
  p.g_k   = (const float*)d_in[12];
  p.be_k  = (const float*)d_in[13];
  p.Wv    = (const float*)d_in[14];
  p.g_v   = (const float*)d_in[15];
  p.be_v  = (const float*)d_in[16];
  p.Wc    = (const float*)d_in[17];
  p.g_c   = (const float*)d_in[18];
  p.be_c  = (const float*)d_in[19];
  p.W_in  = (const float*)d_in[20];
  p.W_rec = (const float*)d_in[21];
  p.W_cls = (const float*)d_in[22];
  p.b_cls = (const float*)d_in[23];

  char* ws = (char*)d_ws;
  p.cnt = (int*)ws;                            // 3 counters, memset below
  p.P1  = (double*)(ws + 256);                 // [20][32] doubles
  p.P2  = (double*)(ws + 256 + 5120);          // [60][32] doubles
  p.P3  = (double*)(ws + 256 + 5120 + 15360);  // [20][32] doubles
  p.out = (float*)d_out;

  (void)hipMemsetAsync(d_ws, 0, 256, stream);  // zero barrier counters
  fused21<<<dim3(B), dim3(NT), 0, stream>>>(p);
}